// Round 1
// baseline (724.515 us; speedup 1.0000x reference)
//
#include <hip/hip_runtime.h>

#define N_NODES 100000
#define N_EDGES 3200000
#define D 128

__device__ __forceinline__ float bf2f(unsigned short u) {
  return __uint_as_float(((unsigned)u) << 16);
}
__device__ __forceinline__ unsigned short f2bf(float f) {
  unsigned u = __float_as_uint(f);
  u += 0x7FFF + ((u >> 16) & 1);   // round-to-nearest-even
  return (unsigned short)(u >> 16);
}

// Detect whether edge_index arrived as int64 (odd int32 words all zero) or int32.
__global__ void detect_kernel(const int* __restrict__ ei32, int* __restrict__ flag) {
  __shared__ int anynz;
  if (threadIdx.x == 0) anynz = 0;
  __syncthreads();
  int v = 0;
  for (int i = threadIdx.x; i < 2048; i += 256) v |= ei32[2 * i + 1];
  if (v) atomicOr(&anynz, 1);
  __syncthreads();
  if (threadIdx.x == 0) *flag = (anynz == 0) ? 1 : 0;
}

__global__ void zero_kernel(int* __restrict__ p, int n) {
  int i = blockIdx.x * blockDim.x + threadIdx.x;
  if (i < n) p[i] = 0;
}

__global__ void count_kernel(const void* __restrict__ edges, const int* __restrict__ flag,
                             int* __restrict__ cnt) {
  const bool is64 = (*flag != 0);
  int stride = gridDim.x * blockDim.x;
  for (int e = blockIdx.x * blockDim.x + threadIdx.x; e < N_EDGES; e += stride) {
    int r = is64 ? (int)((const long long*)edges)[e] : ((const int*)edges)[e];
    atomicAdd(&cnt[r], 1);
  }
}

// Block-level exclusive scan over 1024-element chunks; also emits dinv = rsqrt(deg+1).
__global__ __launch_bounds__(256) void scan1_kernel(const int* __restrict__ cnt,
                                                    int* __restrict__ startArr,
                                                    float* __restrict__ dinv,
                                                    int* __restrict__ partials) {
  __shared__ int s[256];
  int t = threadIdx.x;
  int base = blockIdx.x * 1024 + t * 4;
  int c[4];
#pragma unroll
  for (int i = 0; i < 4; i++) {
    int idx = base + i;
    c[i] = (idx < N_NODES) ? cnt[idx] : 0;
  }
  s[t] = c[0] + c[1] + c[2] + c[3];
  __syncthreads();
#pragma unroll
  for (int off = 1; off < 256; off <<= 1) {
    int v = (t >= off) ? s[t - off] : 0;
    __syncthreads();
    s[t] += v;
    __syncthreads();
  }
  if (t == 255) partials[blockIdx.x] = s[255];
  int run = (t == 0) ? 0 : s[t - 1];
#pragma unroll
  for (int i = 0; i < 4; i++) {
    int idx = base + i;
    if (idx < N_NODES) {
      startArr[idx] = run;
      dinv[idx] = rsqrtf((float)(c[i] + 1));  // +1 self-loop
    }
    run += c[i];
  }
}

__global__ void scan2_kernel(int* __restrict__ partials, int nch) {
  __shared__ int s[128];
  int t = threadIdx.x;
  s[t] = (t < nch) ? partials[t] : 0;
  __syncthreads();
  for (int off = 1; off < 128; off <<= 1) {
    int v = (t >= off) ? s[t - off] : 0;
    __syncthreads();
    s[t] += v;
    __syncthreads();
  }
  partials[t] = (t == 0) ? 0 : s[t - 1];
}

__global__ void scan3_kernel(int* __restrict__ startArr, const int* __restrict__ partials,
                             int* __restrict__ cur) {
  int i = blockIdx.x * blockDim.x + threadIdx.x;
  if (i < N_NODES) {
    int v = startArr[i] + partials[i >> 10];
    startArr[i] = v;
    cur[i] = v;
  }
}

__global__ void fill_kernel(const void* __restrict__ edges, const int* __restrict__ flag,
                            int* __restrict__ cur, int* __restrict__ csr) {
  const bool is64 = (*flag != 0);
  int stride = gridDim.x * blockDim.x;
  for (int e = blockIdx.x * blockDim.x + threadIdx.x; e < N_EDGES; e += stride) {
    int r, c;
    if (is64) {
      r = (int)((const long long*)edges)[e];
      c = (int)((const long long*)edges)[N_EDGES + e];
    } else {
      r = ((const int*)edges)[e];
      c = ((const int*)edges)[N_EDGES + e];
    }
    int pos = atomicAdd(&cur[r], 1);
    csr[pos] = c;
  }
}

// y[n][d] = bf16( dinv[n] * (x @ W)[n][d] )
__global__ __launch_bounds__(256) void gemm_kernel(const float* __restrict__ x,
                                                   const float* __restrict__ W,
                                                   const float* __restrict__ dinv,
                                                   unsigned short* __restrict__ y) {
  __shared__ float xs[32][132];   // [row][k], padded
  __shared__ float ws[32][128];   // [k][col] chunk
  int tid = threadIdx.x;
  int row0 = blockIdx.x * 32;
#pragma unroll
  for (int i = 0; i < 4; i++) {
    int idx = tid + i * 256;
    int m = idx >> 5, c4 = (idx & 31) << 2;
    *(float4*)&xs[m][c4] = *(const float4*)(x + (size_t)(row0 + m) * D + c4);
  }
  float acc[4][4] = {};
  int tx = tid & 31, ty = tid >> 5;  // cols tx*4.., rows ty*4..
  for (int k0 = 0; k0 < 128; k0 += 32) {
#pragma unroll
    for (int i = 0; i < 4; i++) {
      int idx = tid + i * 256;
      int kk = idx >> 5, c4 = (idx & 31) << 2;
      *(float4*)&ws[kk][c4] = *(const float4*)(W + (size_t)(k0 + kk) * D + c4);
    }
    __syncthreads();
#pragma unroll
    for (int k = 0; k < 32; k += 4) {
      float4 a0 = *(float4*)&xs[ty * 4 + 0][k0 + k];
      float4 a1 = *(float4*)&xs[ty * 4 + 1][k0 + k];
      float4 a2 = *(float4*)&xs[ty * 4 + 2][k0 + k];
      float4 a3 = *(float4*)&xs[ty * 4 + 3][k0 + k];
      float4 w0 = *(float4*)&ws[k + 0][tx * 4];
      float4 w1 = *(float4*)&ws[k + 1][tx * 4];
      float4 w2 = *(float4*)&ws[k + 2][tx * 4];
      float4 w3 = *(float4*)&ws[k + 3][tx * 4];
#define ROWFMA(i, ai)                                              \
      acc[i][0] += ai.x * w0.x + ai.y * w1.x + ai.z * w2.x + ai.w * w3.x; \
      acc[i][1] += ai.x * w0.y + ai.y * w1.y + ai.z * w2.y + ai.w * w3.y; \
      acc[i][2] += ai.x * w0.z + ai.y * w1.z + ai.z * w2.z + ai.w * w3.z; \
      acc[i][3] += ai.x * w0.w + ai.y * w1.w + ai.z * w2.w + ai.w * w3.w;
      ROWFMA(0, a0)
      ROWFMA(1, a1)
      ROWFMA(2, a2)
      ROWFMA(3, a3)
#undef ROWFMA
    }
    __syncthreads();
  }
#pragma unroll
  for (int i = 0; i < 4; i++) {
    int row = row0 + ty * 4 + i;
    float di = dinv[row];
    unsigned short h0 = f2bf(di * acc[i][0]);
    unsigned short h1 = f2bf(di * acc[i][1]);
    unsigned short h2 = f2bf(di * acc[i][2]);
    unsigned short h3 = f2bf(di * acc[i][3]);
    uint2 pk;
    pk.x = (unsigned)h0 | ((unsigned)h1 << 16);
    pk.y = (unsigned)h2 | ((unsigned)h3 << 16);
    *(uint2*)(y + (size_t)row * D + tx * 4) = pk;
  }
}

// One wave per node: gather sum_{edges} y[col] + y[self]; agg = dinv*acc + b; LN; ReLU.
__global__ __launch_bounds__(256) void agg_ln_kernel(
    const unsigned short* __restrict__ y, const int* __restrict__ csr,
    const int* __restrict__ startArr, const int* __restrict__ cnt,
    const float* __restrict__ dinv, const float* __restrict__ bias,
    const float* __restrict__ gamma, const float* __restrict__ beta,
    float* __restrict__ out) {
  int wid = threadIdx.x >> 6, lane = threadIdx.x & 63;
  int node = blockIdx.x * 4 + wid;
  if (node >= N_NODES) return;
  const unsigned short* yl = y + 2 * lane;
  int s = startArr[node];
  int n = cnt[node];
  ushort2 sv = *(const ushort2*)(yl + (size_t)node * D);  // self-loop term
  float acc0 = bf2f(sv.x), acc1 = bf2f(sv.y);
  for (int j = 0; j < n; j += 64) {
    int m = n - j;
    if (m > 64) m = 64;
    int cj = (j + lane < n) ? csr[s + j + lane] : 0;
    int t = 0;
    for (; t + 1 < m; t += 2) {   // 2 edges in flight per iter
      int c0 = __shfl(cj, t);
      int c1 = __shfl(cj, t + 1);
      ushort2 v0 = *(const ushort2*)(yl + (size_t)c0 * D);
      ushort2 v1 = *(const ushort2*)(yl + (size_t)c1 * D);
      acc0 += bf2f(v0.x) + bf2f(v1.x);
      acc1 += bf2f(v0.y) + bf2f(v1.y);
    }
    if (t < m) {
      int c0 = __shfl(cj, t);
      ushort2 v0 = *(const ushort2*)(yl + (size_t)c0 * D);
      acc0 += bf2f(v0.x);
      acc1 += bf2f(v0.y);
    }
  }
  float di = dinv[node];
  float v0 = fmaf(di, acc0, bias[2 * lane]);
  float v1 = fmaf(di, acc1, bias[2 * lane + 1]);
  float sum = v0 + v1;
#pragma unroll
  for (int msk = 1; msk <= 32; msk <<= 1) sum += __shfl_xor(sum, msk);
  float mu = sum * (1.0f / 128.0f);
  float d0 = v0 - mu, d1 = v1 - mu;
  float sq = d0 * d0 + d1 * d1;
#pragma unroll
  for (int msk = 1; msk <= 32; msk <<= 1) sq += __shfl_xor(sq, msk);
  float rstd = rsqrtf(sq * (1.0f / 128.0f) + 1e-5f);
  float h0 = fmaxf(fmaf(d0 * rstd, gamma[2 * lane], beta[2 * lane]), 0.0f);
  float h1 = fmaxf(fmaf(d1 * rstd, gamma[2 * lane + 1], beta[2 * lane + 1]), 0.0f);
  float2 o;
  o.x = h0;
  o.y = h1;
  *(float2*)(out + (size_t)node * D + 2 * lane) = o;
}

extern "C" void kernel_launch(void* const* d_in, const int* in_sizes, int n_in,
                              void* d_out, int out_size, void* d_ws, size_t ws_size,
                              hipStream_t stream) {
  const float* x = (const float*)d_in[0];
  const void* edges = d_in[1];
  const float* W = (const float*)d_in[2];
  const float* b = (const float*)d_in[3];
  const float* gamma = (const float*)d_in[4];
  const float* beta = (const float*)d_in[5];
  float* out = (float*)d_out;

  char* w = (char*)d_ws;
  size_t off = 0;
  auto take = [&](size_t bytes) {
    size_t r = off;
    off += (bytes + 255) & ~(size_t)255;
    return r;
  };
  int* flag = (int*)(w + take(256));
  int* cnt = (int*)(w + take((size_t)N_NODES * 4));
  int* startArr = (int*)(w + take((size_t)N_NODES * 4));
  int* cur = (int*)(w + take((size_t)N_NODES * 4));
  float* dinv = (float*)(w + take((size_t)N_NODES * 4));
  int* partials = (int*)(w + take(512));
  int* csr = (int*)(w + take((size_t)N_EDGES * 4));
  unsigned short* y = (unsigned short*)(w + take((size_t)N_NODES * D * 2));

  detect_kernel<<<1, 256, 0, stream>>>((const int*)edges, flag);
  zero_kernel<<<(N_NODES + 255) / 256, 256, 0, stream>>>(cnt, N_NODES);
  count_kernel<<<2048, 256, 0, stream>>>(edges, flag, cnt);
  scan1_kernel<<<98, 256, 0, stream>>>(cnt, startArr, dinv, partials);
  scan2_kernel<<<1, 128, 0, stream>>>(partials, 98);
  scan3_kernel<<<(N_NODES + 255) / 256, 256, 0, stream>>>(startArr, partials, cur);
  fill_kernel<<<2048, 256, 0, stream>>>(edges, flag, cur, csr);
  gemm_kernel<<<N_NODES / 32, 256, 0, stream>>>(x, W, dinv, y);
  agg_ln_kernel<<<(N_NODES + 3) / 4, 256, 0, stream>>>(y, csr, startArr, cnt, dinv, b, gamma,
                                                       beta, out);
}